// Round 1
// baseline (2873.494 us; speedup 1.0000x reference)
//
#include <hip/hip_runtime.h>

#define N_NODES 100000
#define N_EDGES 1600000
#define DIM_IN  256
#define DIM_HID 128
#define DIM_OUT 64

// ---------------- GEMM: C = act(A @ W + bias) ----------------
// A: M x K row-major, W: K x F row-major, C: M x F
#define BM 64
#define BN 64
#define BK 16

__global__ __launch_bounds__(256) void gemm_bias_act(
    const float* __restrict__ A, const float* __restrict__ W,
    const float* __restrict__ bias, float* __restrict__ C,
    int M, int K, int F, int do_relu)
{
    __shared__ float As[BK][BM];
    __shared__ float Ws[BK][BN];
    const int tid = threadIdx.x;
    const int tx = tid & 15;   // n direction
    const int ty = tid >> 4;   // m direction
    const int bm = blockIdx.x * BM;
    const int bn = blockIdx.y * BN;
    float acc[4][4] = {};

    for (int k0 = 0; k0 < K; k0 += BK) {
        for (int i = tid; i < BM * BK; i += 256) {
            int m = i >> 4, kk = i & 15;
            int gm = bm + m;
            As[kk][m] = (gm < M) ? A[(size_t)gm * K + k0 + kk] : 0.0f;
        }
        for (int i = tid; i < BK * BN; i += 256) {
            int kk = i >> 6, n = i & 63;
            Ws[kk][n] = W[(size_t)(k0 + kk) * F + bn + n];
        }
        __syncthreads();
        #pragma unroll
        for (int kk = 0; kk < BK; ++kk) {
            float a[4], w[4];
            #pragma unroll
            for (int i = 0; i < 4; ++i) a[i] = As[kk][ty * 4 + i];
            #pragma unroll
            for (int j = 0; j < 4; ++j) w[j] = Ws[kk][tx * 4 + j];
            #pragma unroll
            for (int i = 0; i < 4; ++i)
                #pragma unroll
                for (int j = 0; j < 4; ++j)
                    acc[i][j] += a[i] * w[j];
        }
        __syncthreads();
    }
    #pragma unroll
    for (int i = 0; i < 4; ++i) {
        int m = bm + ty * 4 + i;
        if (m < M) {
            #pragma unroll
            for (int j = 0; j < 4; ++j) {
                int n = bn + tx * 4 + j;
                float v = acc[i][j] + bias[n];
                if (do_relu) v = fmaxf(v, 0.0f);
                C[(size_t)m * F + n] = v;
            }
        }
    }
}

// ---------------- degree / edge weights ----------------
__global__ void zero_int_kernel(int* __restrict__ p, int n) {
    int i = blockIdx.x * blockDim.x + threadIdx.x;
    if (i < n) p[i] = 0;
}

__global__ void degree_kernel(const int* __restrict__ row, const int* __restrict__ col,
                              int* __restrict__ outdeg, int* __restrict__ indeg, int E) {
    int e = blockIdx.x * blockDim.x + threadIdx.x;
    if (e < E) {
        atomicAdd(&outdeg[row[e]], 1);
        atomicAdd(&indeg[col[e]], 1);
    }
}

__global__ void inv_kernel(const int* __restrict__ outdeg, const int* __restrict__ indeg,
                           float* __restrict__ outinv, float* __restrict__ ininv,
                           float* __restrict__ wself, int n) {
    int i = blockIdx.x * blockDim.x + threadIdx.x;
    if (i < n) {
        // +1 for self-loop; degree always > 0 so no zero-guard branch needed
        float oi = rsqrtf((float)(outdeg[i] + 1));
        float ii = rsqrtf((float)(indeg[i] + 1));
        outinv[i] = oi;
        ininv[i] = ii;
        wself[i] = oi * ii;
    }
}

__global__ void edge_weight_kernel(const int* __restrict__ row, const int* __restrict__ col,
                                   const float* __restrict__ outinv, const float* __restrict__ ininv,
                                   float* __restrict__ w, int E) {
    int e = blockIdx.x * blockDim.x + threadIdx.x;
    if (e < E) w[e] = outinv[row[e]] * ininv[col[e]];
}

// ---------------- conv round ----------------
// init: s_new = s_old + a*wself*t_old ; t_new = t_old + b*wself*s_old  (self-loop term)
__global__ void conv_init_kernel(const float* __restrict__ s_old, const float* __restrict__ t_old,
                                 const float* __restrict__ wself,
                                 float* __restrict__ s_new, float* __restrict__ t_new,
                                 const float* __restrict__ conv_w, int k, int total) {
    int i = blockIdx.x * blockDim.x + threadIdx.x;
    if (i < total) {
        int node = i >> 6;
        float ws = wself[node];
        float a = conv_w[2 * k + 0];
        float b = conv_w[2 * k + 1];
        float sv = s_old[i], tv = t_old[i];
        s_new[i] = sv + a * ws * tv;
        t_new[i] = tv + b * ws * sv;
    }
}

// edges: s_new[row] += a*w*t_old[col]; t_new[col] += b*w*s_old[row]
__global__ void conv_edge_kernel(const int* __restrict__ row, const int* __restrict__ col,
                                 const float* __restrict__ w,
                                 const float* __restrict__ s_old, const float* __restrict__ t_old,
                                 float* __restrict__ s_new, float* __restrict__ t_new,
                                 const float* __restrict__ conv_w, int k, int E) {
    int idx = blockIdx.x * blockDim.x + threadIdx.x;
    int e = idx >> 6;
    int lane = idx & 63;
    if (e < E) {
        int r = row[e], c = col[e];
        float we = w[e];
        float a = conv_w[2 * k + 0] * we;
        float b = conv_w[2 * k + 1] * we;
        atomicAdd(&s_new[(size_t)r * 64 + lane], a * t_old[(size_t)c * 64 + lane]);
        atomicAdd(&t_new[(size_t)c * 64 + lane], b * s_old[(size_t)r * 64 + lane]);
    }
}

extern "C" void kernel_launch(void* const* d_in, const int* in_sizes, int n_in,
                              void* d_out, int out_size, void* d_ws, size_t ws_size,
                              hipStream_t stream) {
    const int N = N_NODES;
    const int E = N_EDGES;

    const float* s_in  = (const float*)d_in[0];
    const float* t_in  = (const float*)d_in[1];
    const int*   ei    = (const int*)d_in[2];
    const int*   row   = ei;
    const int*   col   = ei + E;
    // dict order: Ws0, bs0, Wt0, bt0, Ws1, bs1, Wt1, bt1, Ws2, bs2, Wt2, bt2, conv_w
    const float* Ws0 = (const float*)d_in[3];
    const float* bs0 = (const float*)d_in[4];
    const float* Wt0 = (const float*)d_in[5];
    const float* bt0 = (const float*)d_in[6];
    const float* Ws1 = (const float*)d_in[7];
    const float* bs1 = (const float*)d_in[8];
    const float* Wt1 = (const float*)d_in[9];
    const float* bt1 = (const float*)d_in[10];
    const float* Ws2 = (const float*)d_in[11];
    const float* bs2 = (const float*)d_in[12];
    const float* Wt2 = (const float*)d_in[13];
    const float* bt2 = (const float*)d_in[14];
    const float* conv_w = (const float*)d_in[15];

    float* out_s = (float*)d_out;                       // N*64
    float* out_t = (float*)d_out + (size_t)N * DIM_OUT; // N*64

    // workspace layout (floats)
    float* ws = (float*)d_ws;
    float* H1 = ws;                                  // N*128
    float* H2 = ws + (size_t)N * DIM_HID;            // N*128
    float* S0 = ws + 2 * (size_t)N * DIM_HID;        // N*64
    float* T0 = S0 + (size_t)N * DIM_OUT;            // N*64
    float* S1 = ws;                                  // alias H1 (free after MLPs)
    float* T1 = ws + (size_t)N * DIM_OUT;
    float* EW     = T0 + (size_t)N * DIM_OUT;        // E
    float* WSELF  = EW + E;                          // N
    float* OUTINV = WSELF + N;                       // N
    float* ININV  = OUTINV + N;                      // N
    int*   DEG    = (int*)(ININV + N);               // 2N ints (outdeg, indeg)
    int*   OUTDEG = DEG;
    int*   INDEG  = DEG + N;

    // ---- degrees & edge weights ----
    zero_int_kernel<<<(2 * N + 255) / 256, 256, 0, stream>>>(DEG, 2 * N);
    degree_kernel<<<(E + 255) / 256, 256, 0, stream>>>(row, col, OUTDEG, INDEG, E);
    inv_kernel<<<(N + 255) / 256, 256, 0, stream>>>(OUTDEG, INDEG, OUTINV, ININV, WSELF, N);
    edge_weight_kernel<<<(E + 255) / 256, 256, 0, stream>>>(row, col, OUTINV, ININV, EW, E);

    // ---- MLPs ----
    dim3 blk(256);
    dim3 g1((N + BM - 1) / BM, DIM_HID / BN);  // F=128 -> 2 n-tiles
    dim3 g2((N + BM - 1) / BM, DIM_HID / BN);
    dim3 g3((N + BM - 1) / BM, DIM_OUT / BN);  // F=64 -> 1 n-tile
    // s path
    gemm_bias_act<<<g1, blk, 0, stream>>>(s_in, Ws0, bs0, H1, N, DIM_IN,  DIM_HID, 1);
    gemm_bias_act<<<g2, blk, 0, stream>>>(H1,  Ws1, bs1, H2, N, DIM_HID, DIM_HID, 1);
    gemm_bias_act<<<g3, blk, 0, stream>>>(H2,  Ws2, bs2, S0, N, DIM_HID, DIM_OUT, 0);
    // t path
    gemm_bias_act<<<g1, blk, 0, stream>>>(t_in, Wt0, bt0, H1, N, DIM_IN,  DIM_HID, 1);
    gemm_bias_act<<<g2, blk, 0, stream>>>(H1,  Wt1, bt1, H2, N, DIM_HID, DIM_HID, 1);
    gemm_bias_act<<<g3, blk, 0, stream>>>(H2,  Wt2, bt2, T0, N, DIM_HID, DIM_OUT, 0);

    // ---- 3 conv rounds (double-buffered; last writes d_out) ----
    const int total = N * DIM_OUT;
    const int init_blocks = (total + 255) / 256;
    const int edge_blocks = (int)(((size_t)E * 64 + 255) / 256);

    // round 0: (S0,T0) -> (S1,T1)
    conv_init_kernel<<<init_blocks, 256, 0, stream>>>(S0, T0, WSELF, S1, T1, conv_w, 0, total);
    conv_edge_kernel<<<edge_blocks, 256, 0, stream>>>(row, col, EW, S0, T0, S1, T1, conv_w, 0, E);
    // round 1: (S1,T1) -> (S0,T0)  (reuse)
    conv_init_kernel<<<init_blocks, 256, 0, stream>>>(S1, T1, WSELF, S0, T0, conv_w, 1, total);
    conv_edge_kernel<<<edge_blocks, 256, 0, stream>>>(row, col, EW, S1, T1, S0, T0, conv_w, 1, E);
    // round 2: (S0,T0) -> (out_s, out_t)
    conv_init_kernel<<<init_blocks, 256, 0, stream>>>(S0, T0, WSELF, out_s, out_t, conv_w, 2, total);
    conv_edge_kernel<<<edge_blocks, 256, 0, stream>>>(row, col, EW, S0, T0, out_s, out_t, conv_w, 2, E);
}

// Round 2
// 1655.359 us; speedup vs baseline: 1.7359x; 1.7359x over previous
//
#include <hip/hip_runtime.h>

#define N_NODES 100000
#define N_EDGES 1600000
#define DIM_IN  256
#define DIM_HID 128
#define DIM_OUT 64

// ---------------- GEMM: C = act(A @ W + bias) ----------------
#define BM 64
#define BN 64
#define BK 16

__global__ __launch_bounds__(256) void gemm_bias_act(
    const float* __restrict__ A, const float* __restrict__ W,
    const float* __restrict__ bias, float* __restrict__ C,
    int M, int K, int F, int do_relu)
{
    __shared__ float As[BK][BM];
    __shared__ float Ws[BK][BN];
    const int tid = threadIdx.x;
    const int tx = tid & 15;   // n direction
    const int ty = tid >> 4;   // m direction
    const int bm = blockIdx.x * BM;
    const int bn = blockIdx.y * BN;
    float acc[4][4] = {};

    for (int k0 = 0; k0 < K; k0 += BK) {
        for (int i = tid; i < BM * BK; i += 256) {
            int m = i >> 4, kk = i & 15;
            int gm = bm + m;
            As[kk][m] = (gm < M) ? A[(size_t)gm * K + k0 + kk] : 0.0f;
        }
        for (int i = tid; i < BK * BN; i += 256) {
            int kk = i >> 6, n = i & 63;
            Ws[kk][n] = W[(size_t)(k0 + kk) * F + bn + n];
        }
        __syncthreads();
        #pragma unroll
        for (int kk = 0; kk < BK; ++kk) {
            float a[4], w[4];
            #pragma unroll
            for (int i = 0; i < 4; ++i) a[i] = As[kk][ty * 4 + i];
            #pragma unroll
            for (int j = 0; j < 4; ++j) w[j] = Ws[kk][tx * 4 + j];
            #pragma unroll
            for (int i = 0; i < 4; ++i)
                #pragma unroll
                for (int j = 0; j < 4; ++j)
                    acc[i][j] += a[i] * w[j];
        }
        __syncthreads();
    }
    #pragma unroll
    for (int i = 0; i < 4; ++i) {
        int m = bm + ty * 4 + i;
        if (m < M) {
            #pragma unroll
            for (int j = 0; j < 4; ++j) {
                int n = bn + tx * 4 + j;
                float v = acc[i][j] + bias[n];
                if (do_relu) v = fmaxf(v, 0.0f);
                C[(size_t)m * F + n] = v;
            }
        }
    }
}

// ---------------- degree ----------------
__global__ void zero_int_kernel(int* __restrict__ p, int n) {
    int i = blockIdx.x * blockDim.x + threadIdx.x;
    if (i < n) p[i] = 0;
}

// deg layout: [0,N) = outdeg (row), [N,2N) = indeg (col)
__global__ void degree_kernel(const int* __restrict__ row, const int* __restrict__ col,
                              int* __restrict__ deg, int E, int N) {
    int e = blockIdx.x * blockDim.x + threadIdx.x;
    if (e < E) {
        atomicAdd(&deg[row[e]], 1);
        atomicAdd(&deg[N + col[e]], 1);
    }
}

__global__ void inv_kernel(const int* __restrict__ deg,
                           float* __restrict__ outinv, float* __restrict__ ininv,
                           float* __restrict__ wself, int n) {
    int i = blockIdx.x * blockDim.x + threadIdx.x;
    if (i < n) {
        float oi = rsqrtf((float)(deg[i] + 1));       // +1 self-loop
        float ii = rsqrtf((float)(deg[n + i] + 1));
        outinv[i] = oi;
        ininv[i] = ii;
        wself[i] = oi * ii;
    }
}

// ---------------- exclusive scan over deg[0..n) -> offsets ----------------
__global__ __launch_bounds__(256) void scan_block_kernel(const int* __restrict__ in,
                                                         int* __restrict__ out,
                                                         int* __restrict__ blocksums, int n) {
    __shared__ int tmp[256];
    int tid = threadIdx.x;
    int gid = blockIdx.x * 256 + tid;
    int v = (gid < n) ? in[gid] : 0;
    tmp[tid] = v;
    __syncthreads();
    for (int off = 1; off < 256; off <<= 1) {
        int t = (tid >= off) ? tmp[tid - off] : 0;
        __syncthreads();
        tmp[tid] += t;
        __syncthreads();
    }
    if (gid < n) out[gid] = tmp[tid] - v;   // exclusive
    if (tid == 255) blocksums[blockIdx.x] = tmp[255];
}

__global__ __launch_bounds__(1024) void scan_sums_kernel(int* __restrict__ blocksums, int nb) {
    __shared__ int tmp[1024];
    int tid = threadIdx.x;
    int v = (tid < nb) ? blocksums[tid] : 0;
    tmp[tid] = v;
    __syncthreads();
    for (int off = 1; off < 1024; off <<= 1) {
        int t = (tid >= off) ? tmp[tid - off] : 0;
        __syncthreads();
        tmp[tid] += t;
        __syncthreads();
    }
    if (tid < nb) blocksums[tid] = tmp[tid] - v;  // exclusive block offsets
}

__global__ void add_offsets_kernel(int* __restrict__ out, const int* __restrict__ blocksums, int n) {
    int gid = blockIdx.x * 256 + threadIdx.x;
    if (gid < n) out[gid] += blocksums[blockIdx.x];
}

// ---------------- CSR scatter ----------------
// cursor starts as offsets; after this kernel cursor[i] == segment end.
// csr[0..E): row-CSR (neighbor=col, for s updates); csr[E..2E): col-CSR (neighbor=row, for t updates)
__global__ void build_csr_kernel(const int* __restrict__ row, const int* __restrict__ col,
                                 const float* __restrict__ outinv, const float* __restrict__ ininv,
                                 int* __restrict__ cursor, int2* __restrict__ csr, int E, int N) {
    int e = blockIdx.x * blockDim.x + threadIdx.x;
    if (e < E) {
        int r = row[e], c = col[e];
        float w = outinv[r] * ininv[c];
        int wb = __float_as_int(w);
        int pr = atomicAdd(&cursor[r], 1);
        csr[pr] = make_int2(c, wb);
        int pc = atomicAdd(&cursor[N + c], 1);
        csr[pc] = make_int2(r, wb);
    }
}

// ---------------- fused conv round: gather + self-loop + residual ----------------
// wave (64 lanes) per output node; lanes = feature dim.
// wid in [0,N):  s_new[n] = s_old[n] + a*(wself[n]*t_old[n] + sum w*t_old[col])
// wid in [N,2N): t_new[n] = t_old[n] + b*(wself[n]*s_old[n] + sum w*s_old[row])
__global__ __launch_bounds__(256) void conv_gather_kernel(
    const int* __restrict__ cursor, const int* __restrict__ deg,
    const int2* __restrict__ csr, const float* __restrict__ wself,
    const float* __restrict__ s_old, const float* __restrict__ t_old,
    float* __restrict__ s_new, float* __restrict__ t_new,
    const float* __restrict__ conv_w, int k, int N)
{
    int wid = (int)((blockIdx.x * blockDim.x + threadIdx.x) >> 6);
    int lane = threadIdx.x & 63;
    if (wid >= 2 * N) return;
    int side = (wid >= N) ? 1 : 0;
    int n = side ? wid - N : wid;
    const float* other = side ? s_old : t_old;
    const float* self  = side ? t_old : s_old;
    float* out         = side ? t_new : s_new;
    float coef = conv_w[2 * k + side];

    int end = cursor[wid];
    int d   = deg[wid];
    end = __builtin_amdgcn_readfirstlane(end);
    d   = __builtin_amdgcn_readfirstlane(d);
    int start = end - d;

    float acc = wself[n] * other[(size_t)n * 64 + lane];
    for (int p = start; p < end; ++p) {
        int2 ew = csr[p];
        acc = fmaf(__int_as_float(ew.y), other[(size_t)ew.x * 64 + lane], acc);
    }
    out[(size_t)n * 64 + lane] = fmaf(coef, acc, self[(size_t)n * 64 + lane]);
}

extern "C" void kernel_launch(void* const* d_in, const int* in_sizes, int n_in,
                              void* d_out, int out_size, void* d_ws, size_t ws_size,
                              hipStream_t stream) {
    const int N = N_NODES;
    const int E = N_EDGES;

    const float* s_in  = (const float*)d_in[0];
    const float* t_in  = (const float*)d_in[1];
    const int*   ei    = (const int*)d_in[2];
    const int*   row   = ei;
    const int*   col   = ei + E;
    const float* Ws0 = (const float*)d_in[3];
    const float* bs0 = (const float*)d_in[4];
    const float* Wt0 = (const float*)d_in[5];
    const float* bt0 = (const float*)d_in[6];
    const float* Ws1 = (const float*)d_in[7];
    const float* bs1 = (const float*)d_in[8];
    const float* Wt1 = (const float*)d_in[9];
    const float* bt1 = (const float*)d_in[10];
    const float* Ws2 = (const float*)d_in[11];
    const float* bs2 = (const float*)d_in[12];
    const float* Wt2 = (const float*)d_in[13];
    const float* bt2 = (const float*)d_in[14];
    const float* conv_w = (const float*)d_in[15];

    float* out_s = (float*)d_out;
    float* out_t = (float*)d_out + (size_t)N * DIM_OUT;

    // workspace layout (4-byte units)
    float* ws = (float*)d_ws;
    float* H1 = ws;                                   // N*128 (later S1/T1)
    float* H2 = ws + (size_t)N * DIM_HID;             // N*128
    float* S0 = ws + 2 * (size_t)N * DIM_HID;         // N*64
    float* T0 = S0 + (size_t)N * DIM_OUT;             // N*64
    float* S1 = H1;                                   // alias (free after MLPs)
    float* T1 = H1 + (size_t)N * DIM_OUT;
    int2*  CSR    = (int2*)(T0 + (size_t)N * DIM_OUT);   // 2E int2
    float* OUTINV = (float*)(CSR + 2 * (size_t)E);       // N
    float* ININV  = OUTINV + N;                          // N
    float* WSELF  = ININV + N;                           // N
    int*   DEG    = (int*)(WSELF + N);                   // 2N
    int*   CURSOR = DEG + 2 * N;                         // 2N
    int*   BSUMS  = CURSOR + 2 * N;                      // ~1024

    const int twoN = 2 * N;
    const int scan_blocks = (twoN + 255) / 256;          // 782 <= 1024

    // ---- degrees ----
    zero_int_kernel<<<(twoN + 255) / 256, 256, 0, stream>>>(DEG, twoN);
    degree_kernel<<<(E + 255) / 256, 256, 0, stream>>>(row, col, DEG, E, N);
    inv_kernel<<<(N + 255) / 256, 256, 0, stream>>>(DEG, OUTINV, ININV, WSELF, N);

    // ---- exclusive scan of DEG -> CURSOR (offsets) ----
    scan_block_kernel<<<scan_blocks, 256, 0, stream>>>(DEG, CURSOR, BSUMS, twoN);
    scan_sums_kernel<<<1, 1024, 0, stream>>>(BSUMS, scan_blocks);
    add_offsets_kernel<<<scan_blocks, 256, 0, stream>>>(CURSOR, BSUMS, twoN);

    // ---- CSR scatter (cursor -> ends) ----
    build_csr_kernel<<<(E + 255) / 256, 256, 0, stream>>>(row, col, OUTINV, ININV, CURSOR, CSR, E, N);

    // ---- MLPs ----
    dim3 blk(256);
    dim3 g1((N + BM - 1) / BM, DIM_HID / BN);
    dim3 g3((N + BM - 1) / BM, DIM_OUT / BN);
    gemm_bias_act<<<g1, blk, 0, stream>>>(s_in, Ws0, bs0, H2, N, DIM_IN,  DIM_HID, 1);
    gemm_bias_act<<<g1, blk, 0, stream>>>(H2,  Ws1, bs1, H1, N, DIM_HID, DIM_HID, 1);
    gemm_bias_act<<<g3, blk, 0, stream>>>(H1,  Ws2, bs2, S0, N, DIM_HID, DIM_OUT, 0);
    gemm_bias_act<<<g1, blk, 0, stream>>>(t_in, Wt0, bt0, H2, N, DIM_IN,  DIM_HID, 1);
    gemm_bias_act<<<g1, blk, 0, stream>>>(H2,  Wt1, bt1, H1, N, DIM_HID, DIM_HID, 1);
    gemm_bias_act<<<g3, blk, 0, stream>>>(H1,  Wt2, bt2, T0, N, DIM_HID, DIM_OUT, 0);

    // ---- 3 conv rounds, wave-per-node gather ----
    const int gather_blocks = (twoN * 64 + 255) / 256;   // 4 waves/block
    conv_gather_kernel<<<gather_blocks, 256, 0, stream>>>(CURSOR, DEG, CSR, WSELF, S0, T0, S1, T1, conv_w, 0, N);
    conv_gather_kernel<<<gather_blocks, 256, 0, stream>>>(CURSOR, DEG, CSR, WSELF, S1, T1, S0, T0, conv_w, 1, N);
    conv_gather_kernel<<<gather_blocks, 256, 0, stream>>>(CURSOR, DEG, CSR, WSELF, S0, T0, out_s, out_t, conv_w, 2, N);
}